// Round 9
// baseline (424.843 us; speedup 1.0000x reference)
//
#include <hip/hip_runtime.h>

// Trilinear interpolation of 2M points into a 128x128x128x16 fp32 grid.
// v10: v9 (fp16 grid copy + octet gather + NT residency hints) with ILP:
//  - convert: 2x unrolled (4 NT float4 loads -> 2 f16x8 stores per thread).
//  - interp: 2 points per octet-group -> 8 gather loads in flight per lane
//    (was 4; kernel was latency-exposed at 188us vs 152us modeled wall).
//    Point coords use CACHED loads again (NT bypassed L1, making the
//    octet's 8-fold redundant coordinate reads hit L2 instead of L1).
// Math unchanged: fp32 lerps in v1's exact op order; fp16 only at corners.

#define DD 128
#define HH 128
#define WW 128

typedef float fvec4 __attribute__((ext_vector_type(4)));
typedef _Float16 f16x4 __attribute__((ext_vector_type(4)));
typedef _Float16 f16x8 __attribute__((ext_vector_type(8)));

__device__ __forceinline__ float4 lerp4(float4 a, float4 b, float t) {
    return make_float4(fmaf(b.x - a.x, t, a.x),
                       fmaf(b.y - a.y, t, a.y),
                       fmaf(b.z - a.z, t, a.z),
                       fmaf(b.w - a.w, t, a.w));
}

__device__ __forceinline__ float4 h4f(f16x4 h) {
    return make_float4((float)h[0], (float)h[1], (float)h[2], (float)h[3]);
}

__device__ __forceinline__ f16x8 cvt8(fvec4 a, fvec4 b) {
    f16x8 r;
    r[0] = (_Float16)a.x; r[1] = (_Float16)a.y;
    r[2] = (_Float16)a.z; r[3] = (_Float16)a.w;
    r[4] = (_Float16)b.x; r[5] = (_Float16)b.y;
    r[6] = (_Float16)b.z; r[7] = (_Float16)b.w;
    return r;
}

// ---------------- Pass 1: fp32 grid -> fp16 copy (2x unrolled) ----------------
__global__ __launch_bounds__(256) void convert_f2h(
    const fvec4* __restrict__ in,
    f16x8* __restrict__ o,
    int n8)
{
    int i = (blockIdx.x * 256 + threadIdx.x) * 2;
    if (i >= n8) return;
    // 4 NT loads in flight (fp32 grid is dead after this pass).
    fvec4 a0 = __builtin_nontemporal_load(in + 2 * i);
    fvec4 b0 = __builtin_nontemporal_load(in + 2 * i + 1);
    bool two = (i + 1 < n8);
    fvec4 a1 = a0, b1 = b0;
    if (two) {
        a1 = __builtin_nontemporal_load(in + 2 * i + 2);
        b1 = __builtin_nontemporal_load(in + 2 * i + 3);
    }
    o[i] = cvt8(a0, b0);                 // cached: keep fp16 grid MALL-resident
    if (two) o[i + 1] = cvt8(a1, b1);
}

// ---------------- Pass 2: octet gather, 2 points per group ----------------
// 8 lanes per group: e = q + 4s; q = channel quad, s = z-side. Per (x,y)
// corner the group's 8x8B loads form one contiguous fully-used 64B request.
struct Gat { int a, b, c, d; float xd, yd, zd; };

__device__ __forceinline__ Gat mkgat(float x, float y, float z, int s, int q) {
    float fx = floorf(x), fy = floorf(y), fz = floorf(z);
    int x0 = min(max((int)fx, 0), DD - 1);
    int y0 = min(max((int)fy, 0), HH - 1);
    int z0 = min(max((int)fz, 0), WW - 1);
    int x1 = min(x0 + 1, DD - 1);
    int y1 = min(y0 + 1, HH - 1);
    int z1 = min(z0 + 1, WW - 1);
    int zs = s ? z1 : z0;
    Gat g;
    g.xd = x - (float)x0;
    g.yd = y - (float)y0;
    g.zd = z - (float)z0;
    // Index in 8B units: voxelLinear*4 + q
    g.a = ((((x0 << 7) + y0) << 7) + zs) * 4 + q;
    g.b = ((((x0 << 7) + y1) << 7) + zs) * 4 + q;
    g.c = ((((x1 << 7) + y0) << 7) + zs) * 4 + q;
    g.d = ((((x1 << 7) + y1) << 7) + zs) * 4 + q;
    return g;
}

__global__ __launch_bounds__(256) void trilerp_octet_h2(
    const float* __restrict__ points,
    const f16x4* __restrict__ hv,     // fp16 grid in 8B units: voxel = 4 units
    float4* __restrict__ out,
    int n_points)
{
    int t = blockIdx.x * blockDim.x + threadIdx.x;
    int g = t >> 3;            // point pair group
    int e = t & 7;
    int q = e & 3;             // channel quad
    int s = e >> 2;            // z-side

    int p0 = g << 1;
    if (p0 >= n_points) return;
    int p1 = p0 + 1;
    bool two = (p1 < n_points);

    // Cached loads: L1 serves the 8 redundant lane reads per point.
    float x0c = points[(size_t)p0 * 3 + 0] * 20.0f;   // 1/VOXEL_SIZE = 20
    float y0c = points[(size_t)p0 * 3 + 1] * 20.0f;
    float z0c = points[(size_t)p0 * 3 + 2] * 20.0f;
    float x1c = x0c, y1c = y0c, z1c = z0c;
    if (two) {
        x1c = points[(size_t)p1 * 3 + 0] * 20.0f;
        y1c = points[(size_t)p1 * 3 + 1] * 20.0f;
        z1c = points[(size_t)p1 * 3 + 2] * 20.0f;
    }

    Gat g0 = mkgat(x0c, y0c, z0c, s, q);
    Gat g1 = mkgat(x1c, y1c, z1c, s, q);

    // 8 gather loads in flight.
    float4 A0 = h4f(hv[g0.a]);
    float4 B0 = h4f(hv[g0.b]);
    float4 C0 = h4f(hv[g0.c]);
    float4 D0 = h4f(hv[g0.d]);
    float4 A1 = h4f(hv[g1.a]);
    float4 B1 = h4f(hv[g1.b]);
    float4 C1 = h4f(hv[g1.c]);
    float4 D1 = h4f(hv[g1.d]);

    // v1 op order: s=0 lane computes c0, s=1 lane computes c1.
    float4 u0 = lerp4(A0, C0, g0.xd);
    float4 v0 = lerp4(B0, D0, g0.xd);
    float4 w0 = lerp4(u0, v0, g0.yd);
    float4 u1 = lerp4(A1, C1, g1.xd);
    float4 v1 = lerp4(B1, D1, g1.xd);
    float4 w1 = lerp4(u1, v1, g1.yd);

    // Exchange c0/c1 across z-side lanes (lane ^ 4); all 8 lanes active.
    float4 o0, o1;
    o0.x = __shfl_xor(w0.x, 4);
    o0.y = __shfl_xor(w0.y, 4);
    o0.z = __shfl_xor(w0.z, 4);
    o0.w = __shfl_xor(w0.w, 4);
    o1.x = __shfl_xor(w1.x, 4);
    o1.y = __shfl_xor(w1.y, 4);
    o1.z = __shfl_xor(w1.z, 4);
    o1.w = __shfl_xor(w1.w, 4);

    if (s == 0) {
        float4 r0 = lerp4(w0, o0, g0.zd);
        fvec4 s0 = { r0.x, r0.y, r0.z, r0.w };
        // NT store: wave covers contiguous full 128B lines -> streaming path,
        // zero MALL pollution (MALL stays dedicated to the fp16 grid).
        __builtin_nontemporal_store(s0, (fvec4*)(out + ((size_t)p0 * 4 + q)));
        if (two) {
            float4 r1 = lerp4(w1, o1, g1.zd);
            fvec4 s1 = { r1.x, r1.y, r1.z, r1.w };
            __builtin_nontemporal_store(s1, (fvec4*)(out + ((size_t)p1 * 4 + q)));
        }
    }
}

// ---------------- Fallback: fp32 octet (if workspace too small) ----------------
__global__ __launch_bounds__(256) void trilerp_octet(
    const float* __restrict__ points,
    const float4* __restrict__ values,
    float4* __restrict__ out,
    int n_points)
{
    int t = blockIdx.x * blockDim.x + threadIdx.x;
    int p = t >> 3;
    if (p >= n_points) return;
    int e = t & 7;
    int q = e & 3;
    int s = e >> 2;

    float x = points[p * 3 + 0] * 20.0f;
    float y = points[p * 3 + 1] * 20.0f;
    float z = points[p * 3 + 2] * 20.0f;

    float fx = floorf(x), fy = floorf(y), fz = floorf(z);
    int x0 = min(max((int)fx, 0), DD - 1);
    int y0 = min(max((int)fy, 0), HH - 1);
    int z0 = min(max((int)fz, 0), WW - 1);
    int x1 = min(x0 + 1, DD - 1);
    int y1 = min(y0 + 1, HH - 1);
    int z1 = min(z0 + 1, WW - 1);

    float xd = x - (float)x0;
    float yd = y - (float)y0;
    float zd = z - (float)z0;

    int zs = s ? z1 : z0;

    #define VIDX(xi, yi) ((((((xi) << 7) + (yi)) << 7) + zs) * 4 + q)
    float4 A = values[VIDX(x0, y0)];
    float4 B = values[VIDX(x0, y1)];
    float4 C = values[VIDX(x1, y0)];
    float4 D = values[VIDX(x1, y1)];
    #undef VIDX

    float4 u = lerp4(A, C, xd);
    float4 v = lerp4(B, D, xd);
    float4 w = lerp4(u, v, yd);

    float4 o4;
    o4.x = __shfl_xor(w.x, 4);
    o4.y = __shfl_xor(w.y, 4);
    o4.z = __shfl_xor(w.z, 4);
    o4.w = __shfl_xor(w.w, 4);

    if (s == 0) {
        float4 res = lerp4(w, o4, zd);
        out[(size_t)p * 4 + q] = res;
    }
}

extern "C" void kernel_launch(void* const* d_in, const int* in_sizes, int n_in,
                              void* d_out, int out_size, void* d_ws, size_t ws_size,
                              hipStream_t stream) {
    const float* points = (const float*)d_in[0];
    const float4* values = (const float4*)d_in[1];
    float4* out = (float4*)d_out;

    int n_points = in_sizes[0] / 3;
    int n_floats = in_sizes[1];                  // 128^3 * 16 = 33,554,432
    const size_t h_bytes = (size_t)n_floats * 2; // 64 MiB

    if (d_ws != nullptr && ws_size >= h_bytes) {
        f16x8* hgrid = (f16x8*)d_ws;
        int n8 = n_floats / 8;
        int cblocks = (n8 / 2 + 255) / 256;
        convert_f2h<<<cblocks, 256, 0, stream>>>((const fvec4*)values, hgrid, n8);

        long long groups = (n_points + 1) / 2;
        long long total_threads = groups * 8;
        int gblocks = (int)((total_threads + 255) / 256);
        trilerp_octet_h2<<<gblocks, 256, 0, stream>>>(points, (const f16x4*)d_ws, out, n_points);
    } else {
        long long total_threads = (long long)n_points * 8;
        int gblocks = (int)((total_threads + 255) / 256);
        trilerp_octet<<<gblocks, 256, 0, stream>>>(points, values, out, n_points);
    }
}

// Round 10
// 401.281 us; speedup vs baseline: 1.0587x; 1.0587x over previous
//
#include <hip/hip_runtime.h>

// Trilinear interpolation of 2M points into a 128x128x128x16 fp32 grid.
// v11 == v9 (revert of v10's regression): fp16 grid copy + octet gather +
// NT residency hints. v10's 2-point groups broke full-line NT store coverage
// (WRITE_SIZE 125->142 MB); v9's one-point octets keep a wave's stores
// contiguous over full 128B lines.
//  - convert: NT loads of the fp32 grid (dead after read), cached stores of
//    the fp16 grid (keep it MALL-resident for the gather pass).
//  - interp: NT loads of points, NT stores of out (sequential full lines).
// Math: fp32 lerps in v1's exact op order; fp16 only at corner values.

#define DD 128
#define HH 128
#define WW 128

typedef float fvec4 __attribute__((ext_vector_type(4)));
typedef _Float16 f16x4 __attribute__((ext_vector_type(4)));
typedef _Float16 f16x8 __attribute__((ext_vector_type(8)));

__device__ __forceinline__ float4 lerp4(float4 a, float4 b, float t) {
    return make_float4(fmaf(b.x - a.x, t, a.x),
                       fmaf(b.y - a.y, t, a.y),
                       fmaf(b.z - a.z, t, a.z),
                       fmaf(b.w - a.w, t, a.w));
}

__device__ __forceinline__ float4 h4f(f16x4 h) {
    return make_float4((float)h[0], (float)h[1], (float)h[2], (float)h[3]);
}

// ---------------- Pass 1: fp32 grid -> fp16 copy (streaming) ----------------
__global__ __launch_bounds__(256) void convert_f2h(
    const fvec4* __restrict__ in,
    f16x8* __restrict__ o,
    int n8)
{
    int i = blockIdx.x * 256 + threadIdx.x;
    if (i >= n8) return;
    fvec4 a = __builtin_nontemporal_load(in + 2 * i);       // dead after read
    fvec4 b = __builtin_nontemporal_load(in + 2 * i + 1);
    f16x8 r;
    r[0] = (_Float16)a.x; r[1] = (_Float16)a.y;
    r[2] = (_Float16)a.z; r[3] = (_Float16)a.w;
    r[4] = (_Float16)b.x; r[5] = (_Float16)b.y;
    r[6] = (_Float16)b.z; r[7] = (_Float16)b.w;
    o[i] = r;                                               // cached: keep in MALL
}

// ---------------- Pass 2: octet gather from the fp16 grid ----------------
// 8 lanes per point: e = q + 4s; q = channel quad, s = z-side. Per (x,y)
// corner the octet's 8x8B loads form one contiguous fully-used 64B request.
__global__ __launch_bounds__(256) void trilerp_octet_h(
    const float* __restrict__ points,
    const f16x4* __restrict__ hv,     // fp16 grid in 8B units: voxel = 4 units
    float4* __restrict__ out,
    int n_points)
{
    int t = blockIdx.x * blockDim.x + threadIdx.x;
    int p = t >> 3;
    if (p >= n_points) return;
    int e = t & 7;
    int q = e & 3;             // channel quad
    int s = e >> 2;            // z-side

    const float* pp = points + (size_t)p * 3;
    float x = __builtin_nontemporal_load(pp + 0) * 20.0f;   // 1/VOXEL_SIZE = 20
    float y = __builtin_nontemporal_load(pp + 1) * 20.0f;
    float z = __builtin_nontemporal_load(pp + 2) * 20.0f;

    float fx = floorf(x), fy = floorf(y), fz = floorf(z);
    int x0 = min(max((int)fx, 0), DD - 1);
    int y0 = min(max((int)fy, 0), HH - 1);
    int z0 = min(max((int)fz, 0), WW - 1);
    int x1 = min(x0 + 1, DD - 1);
    int y1 = min(y0 + 1, HH - 1);
    int z1 = min(z0 + 1, WW - 1);

    float xd = x - (float)x0;
    float yd = y - (float)y0;
    float zd = z - (float)z0;

    int zs = s ? z1 : z0;

    // Index in 8B units: voxelLinear*4 + q
    #define HIDX(xi, yi) ((((((xi) << 7) + (yi)) << 7) + zs) * 4 + q)
    float4 A = h4f(hv[HIDX(x0, y0)]);   // c00s
    float4 B = h4f(hv[HIDX(x0, y1)]);   // c01s
    float4 C = h4f(hv[HIDX(x1, y0)]);   // c10s
    float4 D = h4f(hv[HIDX(x1, y1)]);   // c11s
    #undef HIDX

    // v1 op order: s=0 lane computes c0, s=1 lane computes c1.
    float4 u = lerp4(A, C, xd);
    float4 v = lerp4(B, D, xd);
    float4 w = lerp4(u, v, yd);

    // Exchange c0/c1 across z-side lanes (lane ^ 4); all 8 lanes active.
    float4 o4;
    o4.x = __shfl_xor(w.x, 4);
    o4.y = __shfl_xor(w.y, 4);
    o4.z = __shfl_xor(w.z, 4);
    o4.w = __shfl_xor(w.w, 4);

    if (s == 0) {
        float4 res = lerp4(w, o4, zd);
        fvec4 rv = { res.x, res.y, res.z, res.w };
        // NT store: wave's active lanes cover contiguous full 128B lines ->
        // streaming write path, no MALL pollution (out is dead data).
        __builtin_nontemporal_store(rv, (fvec4*)(out + ((size_t)p * 4 + q)));
    }
}

// ---------------- Fallback: fp32 octet (if workspace too small) ----------------
__global__ __launch_bounds__(256) void trilerp_octet(
    const float* __restrict__ points,
    const float4* __restrict__ values,
    float4* __restrict__ out,
    int n_points)
{
    int t = blockIdx.x * blockDim.x + threadIdx.x;
    int p = t >> 3;
    if (p >= n_points) return;
    int e = t & 7;
    int q = e & 3;
    int s = e >> 2;

    float x = points[p * 3 + 0] * 20.0f;
    float y = points[p * 3 + 1] * 20.0f;
    float z = points[p * 3 + 2] * 20.0f;

    float fx = floorf(x), fy = floorf(y), fz = floorf(z);
    int x0 = min(max((int)fx, 0), DD - 1);
    int y0 = min(max((int)fy, 0), HH - 1);
    int z0 = min(max((int)fz, 0), WW - 1);
    int x1 = min(x0 + 1, DD - 1);
    int y1 = min(y0 + 1, HH - 1);
    int z1 = min(z0 + 1, WW - 1);

    float xd = x - (float)x0;
    float yd = y - (float)y0;
    float zd = z - (float)z0;

    int zs = s ? z1 : z0;

    #define VIDX(xi, yi) ((((((xi) << 7) + (yi)) << 7) + zs) * 4 + q)
    float4 A = values[VIDX(x0, y0)];
    float4 B = values[VIDX(x0, y1)];
    float4 C = values[VIDX(x1, y0)];
    float4 D = values[VIDX(x1, y1)];
    #undef VIDX

    float4 u = lerp4(A, C, xd);
    float4 v = lerp4(B, D, xd);
    float4 w = lerp4(u, v, yd);

    float4 o4;
    o4.x = __shfl_xor(w.x, 4);
    o4.y = __shfl_xor(w.y, 4);
    o4.z = __shfl_xor(w.z, 4);
    o4.w = __shfl_xor(w.w, 4);

    if (s == 0) {
        float4 res = lerp4(w, o4, zd);
        out[(size_t)p * 4 + q] = res;
    }
}

extern "C" void kernel_launch(void* const* d_in, const int* in_sizes, int n_in,
                              void* d_out, int out_size, void* d_ws, size_t ws_size,
                              hipStream_t stream) {
    const float* points = (const float*)d_in[0];
    const float4* values = (const float4*)d_in[1];
    float4* out = (float4*)d_out;

    int n_points = in_sizes[0] / 3;
    int n_floats = in_sizes[1];                  // 128^3 * 16 = 33,554,432
    const size_t h_bytes = (size_t)n_floats * 2; // 64 MiB

    long long total_threads = (long long)n_points * 8;
    int gblocks = (int)((total_threads + 255) / 256);

    if (d_ws != nullptr && ws_size >= h_bytes) {
        f16x8* hgrid = (f16x8*)d_ws;
        int n8 = n_floats / 8;
        int cblocks = (n8 + 255) / 256;
        convert_f2h<<<cblocks, 256, 0, stream>>>((const fvec4*)values, hgrid, n8);
        trilerp_octet_h<<<gblocks, 256, 0, stream>>>(points, (const f16x4*)d_ws, out, n_points);
    } else {
        trilerp_octet<<<gblocks, 256, 0, stream>>>(points, values, out, n_points);
    }
}